// Round 2
// baseline (253.470 us; speedup 1.0000x reference)
//
#include <hip/hip_runtime.h>

// Dtype contract (established round 1): device buffers are FP32 (per the
// reference dtypes); the "(bf16, ...)" in the test label is the comparison
// tolerance mode (2% of absmax + bf16 floor), not the buffer dtype.
// Internal compute: bf16 MFMA, fp32 accumulate.

#define BATCH 8
#define SEQ   2048
#define CIN   1024
#define HDIM  64

typedef __attribute__((ext_vector_type(8))) short bf16x8;
typedef __attribute__((ext_vector_type(4))) float f32x4;

__device__ __forceinline__ unsigned short f2bf(float f) {
  unsigned int u = __builtin_bit_cast(unsigned int, f);
  u += 0x7fffu + ((u >> 16) & 1u);          // RNE
  return (unsigned short)(u >> 16);
}
__device__ __forceinline__ float bf2f(unsigned short h) {
  return __builtin_bit_cast(float, (unsigned int)h << 16);
}
__device__ __forceinline__ bf16x8 pack8(f32x4 a, f32x4 b) {
  bf16x8 r;
  r[0] = (short)f2bf(a[0]); r[1] = (short)f2bf(a[1]);
  r[2] = (short)f2bf(a[2]); r[3] = (short)f2bf(a[3]);
  r[4] = (short)f2bf(b[0]); r[5] = (short)f2bf(b[1]);
  r[6] = (short)f2bf(b[2]); r[7] = (short)f2bf(b[3]);
  return r;
}

// ---------------- Kernel 0: W [C][HD] fp32 -> Wt [HD][C] bf16, 3 matrices ---
__global__ __launch_bounds__(256) void wtrans_k(const float* __restrict__ wq,
                                                const float* __restrict__ wk,
                                                const float* __restrict__ wv,
                                                unsigned short* __restrict__ wt) {
  int idx = blockIdx.x * 256 + threadIdx.x;        // 0 .. 3*65536-1
  int m   = idx >> 16;
  int rem = idx & 65535;
  int c   = rem >> 6;
  int n   = rem & 63;
  const float* w = (m == 0) ? wq : (m == 1) ? wk : wv;
  wt[m * 65536 + n * CIN + c] = f2bf(w[c * HDIM + n]);
}

// ---------------- Kernel 1: fused QKV projection ----------------------------
// grid: (B*T)/64 blocks of 256 threads; wave w -> 16 rows.
// q [B*T][64] bf16 (pre-scaled by 1/sqrt(C)=1/32), k [B*T][64] bf16,
// v transposed vt [B][64][T] bf16.
__global__ __launch_bounds__(256) void qkv_proj_k(const float* __restrict__ x,
                                                  const unsigned short* __restrict__ wt,
                                                  unsigned short* __restrict__ q,
                                                  unsigned short* __restrict__ k,
                                                  unsigned short* __restrict__ vt) {
  const int lane = threadIdx.x & 63;
  const int w    = threadIdx.x >> 6;
  const int lr   = lane & 15, lg = lane >> 4;
  const int row0 = blockIdx.x * 64 + w * 16;

  f32x4 acc[12];
#pragma unroll
  for (int i = 0; i < 12; ++i) acc[i] = (f32x4){0.f, 0.f, 0.f, 0.f};

  const float* xrow = x + (size_t)(row0 + lr) * CIN;
#pragma unroll 1
  for (int ks = 0; ks < CIN; ks += 32) {
    f32x4 xa = *(const f32x4*)(xrow + ks + lg * 8);
    f32x4 xb = *(const f32x4*)(xrow + ks + lg * 8 + 4);
    bf16x8 a = pack8(xa, xb);
#pragma unroll
    for (int m = 0; m < 3; ++m) {
#pragma unroll
      for (int n = 0; n < 4; ++n) {
        bf16x8 bfr = *(const bf16x8*)(wt + m * 65536 + (n * 16 + lr) * CIN + ks + lg * 8);
        acc[m * 4 + n] = __builtin_amdgcn_mfma_f32_16x16x32_bf16(a, bfr, acc[m * 4 + n], 0, 0, 0);
      }
    }
  }
  // C/D layout: row=(lane>>4)*4+j, col=lane&15  [verified m89/m91]
#pragma unroll
  for (int n = 0; n < 4; ++n) {
#pragma unroll
    for (int j = 0; j < 4; ++j) {
      int grow = row0 + lg * 4 + j;
      int hd   = n * 16 + lr;
      q[(size_t)grow * HDIM + hd] = f2bf(acc[n][j] * 0.03125f);   // fold 1/sqrt(C)
      k[(size_t)grow * HDIM + hd] = f2bf(acc[4 + n][j]);
      int b = grow >> 11, t = grow & 2047;
      vt[((size_t)b * HDIM + hd) * SEQ + t] = f2bf(acc[8 + n][j]);
    }
  }
}

// ---------------- Kernel 2: causal flash attention --------------------------
// 1 wave (64 thr) per block; 1024 blocks = (B*T)/16 q-tiles.
// Swapped QK^T: S^T = mfma(K_frag, Q^T_frag) so lane lr owns q-row lr's scores.
__global__ __launch_bounds__(64) void attn_k(const unsigned short* __restrict__ q,
                                             const unsigned short* __restrict__ k,
                                             const unsigned short* __restrict__ vt,
                                             float* __restrict__ out) {
  __shared__ __align__(16) unsigned short plds[16][56];  // 112B stride: 16B-aligned, 2-way banks (free)
  const int lane = threadIdx.x;
  const int lr = lane & 15, lg = lane >> 4;
  const int wid = blockIdx.x;
  const int b   = wid & 7;
  const int qt  = 127 - (wid >> 3);         // longest q-tiles launch first
  const int row0 = qt * 16;

  const unsigned short* qb_ = q  + (size_t)b * SEQ * HDIM;
  const unsigned short* kb_ = k  + (size_t)b * SEQ * HDIM;
  const unsigned short* vb_ = vt + (size_t)b * HDIM * SEQ;

  // Q^T B-fragments, hoisted: lane -> Q[row0+lr][lg*8 .. +8]
  bf16x8 qf0 = *(const bf16x8*)(qb_ + (row0 + lr) * HDIM + lg * 8);
  bf16x8 qf1 = *(const bf16x8*)(qb_ + (row0 + lr) * HDIM + 32 + lg * 8);

  f32x4 o[4];
#pragma unroll
  for (int n = 0; n < 4; ++n) o[n] = (f32x4){0.f, 0.f, 0.f, 0.f};
  float m_run = -INFINITY, l_run = 0.f;
  const int   qrow = row0 + lr;
  const float LOG2E = 1.44269504f;
  const int nt = (row0 + 47) >> 5;          // ceil((row0+16)/32) KV tiles of 32

  for (int t = 0; t < nt; ++t) {
    const int kv = t * 32;
    f32x4 s0 = (f32x4){0.f, 0.f, 0.f, 0.f};
    f32x4 s1 = (f32x4){0.f, 0.f, 0.f, 0.f};
    {
      bf16x8 ka0 = *(const bf16x8*)(kb_ + (kv + lr) * HDIM + lg * 8);
      bf16x8 ka1 = *(const bf16x8*)(kb_ + (kv + lr) * HDIM + 32 + lg * 8);
      s0 = __builtin_amdgcn_mfma_f32_16x16x32_bf16(ka0, qf0, s0, 0, 0, 0);
      s0 = __builtin_amdgcn_mfma_f32_16x16x32_bf16(ka1, qf1, s0, 0, 0, 0);
      bf16x8 kc0 = *(const bf16x8*)(kb_ + (kv + 16 + lr) * HDIM + lg * 8);
      bf16x8 kc1 = *(const bf16x8*)(kb_ + (kv + 16 + lr) * HDIM + 32 + lg * 8);
      s1 = __builtin_amdgcn_mfma_f32_16x16x32_bf16(kc0, qf0, s1, 0, 0, 0);
      s1 = __builtin_amdgcn_mfma_f32_16x16x32_bf16(kc1, qf1, s1, 0, 0, 0);
    }
    // lane (lr,lg) reg j holds S[q=row0+lr][key = kv + {0,16} + lg*4 + j]
#pragma unroll
    for (int j = 0; j < 4; ++j) {
      int key0 = kv + lg * 4 + j;
      if (key0 > qrow)      s0[j] = -INFINITY;
      if (key0 + 16 > qrow) s1[j] = -INFINITY;
    }
    float tm = fmaxf(fmaxf(fmaxf(s0[0], s0[1]), fmaxf(s0[2], s0[3])),
                     fmaxf(fmaxf(s1[0], s1[1]), fmaxf(s1[2], s1[3])));
    tm = fmaxf(tm, __shfl_xor(tm, 16, 64));
    tm = fmaxf(tm, __shfl_xor(tm, 32, 64));
    float m_new = fmaxf(m_run, tm);
    float alpha = exp2f((m_run - m_new) * LOG2E);
    float mc = m_new * LOG2E;
    float ps = 0.f;
#pragma unroll
    for (int j = 0; j < 4; ++j) {
      float p0 = exp2f(s0[j] * LOG2E - mc);
      float p1 = exp2f(s1[j] * LOG2E - mc);
      unsigned short r0 = f2bf(p0), r1 = f2bf(p1);
      plds[lr][lg * 4 + j]      = r0;
      plds[lr][16 + lg * 4 + j] = r1;
      ps += bf2f(r0) + bf2f(r1);            // sum exactly what PV consumes
    }
    ps += __shfl_xor(ps, 16, 64);
    ps += __shfl_xor(ps, 32, 64);
    l_run = l_run * alpha + ps;
    m_run = m_new;
    // O rows are q_local = lg*4+j; alpha lives at lane (q_local)
#pragma unroll
    for (int j = 0; j < 4; ++j) {
      float aj = __shfl(alpha, lg * 4 + j, 64);
      o[0][j] *= aj; o[1][j] *= aj; o[2][j] *= aj; o[3][j] *= aj;
    }
    __syncthreads();   // 1 wave: near-free; orders P LDS writes before reads
    // PV: A = P[q=lr][key contiguous] from LDS; B = V via vt (contiguous in t)
    bf16x8 pf = *(const bf16x8*)(&plds[lr][lg * 8]);
#pragma unroll
    for (int n = 0; n < 4; ++n) {
      bf16x8 vf = *(const bf16x8*)(vb_ + (n * 16 + lr) * SEQ + kv + lg * 8);
      o[n] = __builtin_amdgcn_mfma_f32_16x16x32_bf16(pf, vf, o[n], 0, 0, 0);
    }
  }

  float linv = 1.f / l_run;                  // valid in lanes where lr = q_local
#pragma unroll
  for (int j = 0; j < 4; ++j) {
    float lj = __shfl(linv, lg * 4 + j, 64);
    int grow = b * SEQ + row0 + lg * 4 + j;
#pragma unroll
    for (int n = 0; n < 4; ++n)
      out[(size_t)grow * HDIM + n * 16 + lr] = o[n][j] * lj;
  }
}

// ---------------- launch ----------------------------------------------------
extern "C" void kernel_launch(void* const* d_in, const int* in_sizes, int n_in,
                              void* d_out, int out_size, void* d_ws, size_t ws_size,
                              hipStream_t stream) {
  const float* x  = (const float*)d_in[0];
  const float* wq = (const float*)d_in[1];
  const float* wk = (const float*)d_in[2];
  const float* wv = (const float*)d_in[3];
  float* outp = (float*)d_out;

  unsigned short* ws = (unsigned short*)d_ws;
  const size_t NROW = (size_t)BATCH * SEQ;          // 16384
  unsigned short* qbuf = ws;                        // [NROW][64] bf16
  unsigned short* kbuf = ws + NROW * HDIM;          // [NROW][64] bf16
  unsigned short* vbuf = ws + 2 * NROW * HDIM;      // [B][64][T] bf16
  unsigned short* wt   = ws + 3 * NROW * HDIM;      // [3][64][1024] bf16

  hipLaunchKernelGGL(wtrans_k, dim3(768), dim3(256), 0, stream, wq, wk, wv, wt);
  hipLaunchKernelGGL(qkv_proj_k, dim3(NROW / 64), dim3(256), 0, stream, x, wt, qbuf, kbuf, vbuf);
  hipLaunchKernelGGL(attn_k, dim3(NROW / 16), dim3(64), 0, stream, qbuf, kbuf, vbuf, outp);
}

// Round 3
// 189.211 us; speedup vs baseline: 1.3396x; 1.3396x over previous
//
#include <hip/hip_runtime.h>

// Dtype contract: device buffers FP32 (reference dtypes); internal bf16 MFMA,
// fp32 accumulate. Tolerance is bf16-grade (2% of absmax).

#define BATCH 8
#define SEQ   2048
#define CIN   1024
#define HDIM  64
#define NROW  (BATCH * SEQ)      // 16384
#define NQT   (NROW / 16)        // 1024 q-tiles

typedef __attribute__((ext_vector_type(8))) short bf16x8;
typedef __attribute__((ext_vector_type(4))) float f32x4;

__device__ __forceinline__ unsigned short f2bf(float f) {
  unsigned int u = __builtin_bit_cast(unsigned int, f);
  u += 0x7fffu + ((u >> 16) & 1u);          // RNE
  return (unsigned short)(u >> 16);
}
__device__ __forceinline__ float bf2f(unsigned short h) {
  return __builtin_bit_cast(float, (unsigned int)h << 16);
}
__device__ __forceinline__ bf16x8 pack8(f32x4 a, f32x4 b) {
  bf16x8 r;
  r[0] = (short)f2bf(a[0]); r[1] = (short)f2bf(a[1]);
  r[2] = (short)f2bf(a[2]); r[3] = (short)f2bf(a[3]);
  r[4] = (short)f2bf(b[0]); r[5] = (short)f2bf(b[1]);
  r[6] = (short)f2bf(b[2]); r[7] = (short)f2bf(b[3]);
  return r;
}

// ---------------- Kernel 0: W [C][HD] fp32 -> Wt [HD][C] bf16 (LDS tiles) ---
// grid 48 blocks: m (3) x 16 c-tiles of 64.
__global__ __launch_bounds__(256) void wtrans_k(const float* __restrict__ wq,
                                                const float* __restrict__ wk,
                                                const float* __restrict__ wv,
                                                unsigned short* __restrict__ wt) {
  __shared__ unsigned short lds[64][65];
  const int m  = blockIdx.x >> 4;
  const int c0 = (blockIdx.x & 15) * 64;
  const float* w = (m == 0) ? wq : (m == 1) ? wk : wv;
  const int nl = threadIdx.x & 63, gr = threadIdx.x >> 6;
#pragma unroll
  for (int i = 0; i < 16; ++i) {
    int cl = gr * 16 + i;
    lds[cl][nl] = f2bf(w[(size_t)(c0 + cl) * HDIM + nl]);   // coalesced read
  }
  __syncthreads();
#pragma unroll
  for (int i = 0; i < 16; ++i) {
    int n = gr * 16 + i;
    wt[(size_t)m * 65536 + n * CIN + c0 + nl] = lds[nl][n]; // coalesced write
  }
}

// ---------------- Kernel 1: fused QKV projection, K-split x4 ----------------
// grid NROW/16 = 1024 blocks x 256 thr. Block = 16 rows; wave kc owns K-chunk
// [kc*256, kc*256+256). LDS tree-reduce, wave 0 stores.
__global__ __launch_bounds__(256) void qkv_proj_k(const float* __restrict__ x,
                                                  const unsigned short* __restrict__ wt,
                                                  unsigned short* __restrict__ q,
                                                  unsigned short* __restrict__ k,
                                                  unsigned short* __restrict__ vt) {
  __shared__ f32x4 red[2][12][64];                  // 24.6 KB
  const int lane = threadIdx.x & 63;
  const int kc   = threadIdx.x >> 6;
  const int lr   = lane & 15, lg = lane >> 4;
  const int row0 = blockIdx.x * 16;

  f32x4 acc[12];
#pragma unroll
  for (int i = 0; i < 12; ++i) acc[i] = (f32x4){0.f, 0.f, 0.f, 0.f};

  const float* xrow = x + (size_t)(row0 + lr) * CIN + kc * 256;
  const unsigned short* wbase = wt + kc * 256 + lg * 8;
#pragma unroll 2
  for (int ks = 0; ks < 256; ks += 32) {
    f32x4 xa = *(const f32x4*)(xrow + ks + lg * 8);
    f32x4 xb = *(const f32x4*)(xrow + ks + lg * 8 + 4);
    bf16x8 a = pack8(xa, xb);
#pragma unroll
    for (int m = 0; m < 3; ++m) {
#pragma unroll
      for (int n = 0; n < 4; ++n) {
        bf16x8 bfr = *(const bf16x8*)(wbase + m * 65536 + (n * 16 + lr) * CIN + ks);
        acc[m * 4 + n] = __builtin_amdgcn_mfma_f32_16x16x32_bf16(a, bfr, acc[m * 4 + n], 0, 0, 0);
      }
    }
  }
  if (kc >= 2) {
#pragma unroll
    for (int a = 0; a < 12; ++a) red[kc - 2][a][lane] = acc[a];
  }
  __syncthreads();
  if (kc < 2) {
#pragma unroll
    for (int a = 0; a < 12; ++a) acc[a] += red[kc][a][lane];
  }
  __syncthreads();
  if (kc == 1) {
#pragma unroll
    for (int a = 0; a < 12; ++a) red[0][a][lane] = acc[a];
  }
  __syncthreads();
  if (kc == 0) {
#pragma unroll
    for (int a = 0; a < 12; ++a) acc[a] += red[0][a][lane];
    // C/D layout: row = lg*4+j, col = lr  [m89/m91]
#pragma unroll
    for (int n = 0; n < 4; ++n) {
#pragma unroll
      for (int j = 0; j < 4; ++j) {
        int grow = row0 + lg * 4 + j;
        int hd   = n * 16 + lr;
        q[(size_t)grow * HDIM + hd] = f2bf(acc[n][j] * 0.03125f);  // fold 1/sqrt(C)
        k[(size_t)grow * HDIM + hd] = f2bf(acc[4 + n][j]);
        int b = grow >> 11, t = grow & 2047;
        vt[((size_t)b * HDIM + hd) * SEQ + t] = f2bf(acc[8 + n][j]);
      }
    }
  }
}

// ---------------- Kernel 2: causal flash attention, split-KV ----------------
// grid = NQT * S blocks x 64 thr. Wave = (b, qt, seg s of the key range).
// Writes unnormalized O partial + (m, l) to ws; combine_k merges.
__global__ __launch_bounds__(64) void attn_k(const unsigned short* __restrict__ q,
                                             const unsigned short* __restrict__ k,
                                             const unsigned short* __restrict__ vt,
                                             float* __restrict__ opart,
                                             float* __restrict__ m_l,
                                             int S) {
  __shared__ __align__(16) unsigned short plds[16][56];
  const int lane = threadIdx.x;
  const int lr = lane & 15, lg = lane >> 4;
  const int blk  = blockIdx.x;
  const int b    = blk & 7;
  const int rest = blk >> 3;
  const int s    = rest % S;
  const int qt   = 127 - rest / S;          // longest q-tiles first
  const int row0 = qt * 16;
  const int p    = (b * 128 + qt) * S + s;

  const unsigned short* qb_ = q  + (size_t)b * SEQ * HDIM;
  const unsigned short* kb_ = k  + (size_t)b * SEQ * HDIM;
  const unsigned short* vb_ = vt + (size_t)b * HDIM * SEQ;

  bf16x8 qf0 = *(const bf16x8*)(qb_ + (row0 + lr) * HDIM + lg * 8);
  bf16x8 qf1 = *(const bf16x8*)(qb_ + (row0 + lr) * HDIM + 32 + lg * 8);

  f32x4 o[4];
#pragma unroll
  for (int n = 0; n < 4; ++n) o[n] = (f32x4){0.f, 0.f, 0.f, 0.f};
  float m_run = -INFINITY, l_run = 0.f;
  const int   qrow = row0 + lr;
  const float LOG2E = 1.44269504f;
  const int nt = (row0 + 47) >> 5;          // ceil((row0+16)/32) KV tiles of 32
  const int lo = (nt * s) / S;
  const int hi = (nt * (s + 1)) / S;

  for (int t = lo; t < hi; ++t) {
    const int kv = t * 32;
    f32x4 s0 = (f32x4){0.f, 0.f, 0.f, 0.f};
    f32x4 s1 = (f32x4){0.f, 0.f, 0.f, 0.f};
    {
      bf16x8 ka0 = *(const bf16x8*)(kb_ + (kv + lr) * HDIM + lg * 8);
      bf16x8 ka1 = *(const bf16x8*)(kb_ + (kv + lr) * HDIM + 32 + lg * 8);
      s0 = __builtin_amdgcn_mfma_f32_16x16x32_bf16(ka0, qf0, s0, 0, 0, 0);
      s0 = __builtin_amdgcn_mfma_f32_16x16x32_bf16(ka1, qf1, s0, 0, 0, 0);
      bf16x8 kc0 = *(const bf16x8*)(kb_ + (kv + 16 + lr) * HDIM + lg * 8);
      bf16x8 kc1 = *(const bf16x8*)(kb_ + (kv + 16 + lr) * HDIM + 32 + lg * 8);
      s1 = __builtin_amdgcn_mfma_f32_16x16x32_bf16(kc0, qf0, s1, 0, 0, 0);
      s1 = __builtin_amdgcn_mfma_f32_16x16x32_bf16(kc1, qf1, s1, 0, 0, 0);
    }
#pragma unroll
    for (int j = 0; j < 4; ++j) {
      int key0 = kv + lg * 4 + j;
      if (key0 > qrow)      s0[j] = -INFINITY;
      if (key0 + 16 > qrow) s1[j] = -INFINITY;
    }
    float tm = fmaxf(fmaxf(fmaxf(s0[0], s0[1]), fmaxf(s0[2], s0[3])),
                     fmaxf(fmaxf(s1[0], s1[1]), fmaxf(s1[2], s1[3])));
    tm = fmaxf(tm, __shfl_xor(tm, 16, 64));
    tm = fmaxf(tm, __shfl_xor(tm, 32, 64));
    float m_new = fmaxf(m_run, tm);
    // Guards: segment may start fully masked for this row (m stays -inf).
    float alpha = (m_run == -INFINITY) ? 0.f : exp2f((m_run - m_new) * LOG2E);
    float mc    = (m_new == -INFINITY) ? 0.f : m_new * LOG2E;
    float ps = 0.f;
#pragma unroll
    for (int j = 0; j < 4; ++j) {
      float p0 = exp2f(s0[j] * LOG2E - mc);
      float p1 = exp2f(s1[j] * LOG2E - mc);
      unsigned short r0 = f2bf(p0), r1 = f2bf(p1);
      plds[lr][lg * 4 + j]      = r0;
      plds[lr][16 + lg * 4 + j] = r1;
      ps += bf2f(r0) + bf2f(r1);
    }
    ps += __shfl_xor(ps, 16, 64);
    ps += __shfl_xor(ps, 32, 64);
    l_run = l_run * alpha + ps;
    m_run = m_new;
#pragma unroll
    for (int j = 0; j < 4; ++j) {
      float aj = __shfl(alpha, lg * 4 + j, 64);
      o[0][j] *= aj; o[1][j] *= aj; o[2][j] *= aj; o[3][j] *= aj;
    }
    __syncthreads();
    bf16x8 pf = *(const bf16x8*)(&plds[lr][lg * 8]);
#pragma unroll
    for (int n = 0; n < 4; ++n) {
      bf16x8 vf = *(const bf16x8*)(vb_ + (n * 16 + lr) * SEQ + kv + lg * 8);
      o[n] = __builtin_amdgcn_mfma_f32_16x16x32_bf16(pf, vf, o[n], 0, 0, 0);
    }
  }

  if (lane < 16) {
    m_l[p * 32 + lane]      = m_run;
    m_l[p * 32 + 16 + lane] = l_run;
  }
#pragma unroll
  for (int j = 0; j < 4; ++j) {
    int r = lg * 4 + j;
#pragma unroll
    for (int n = 0; n < 4; ++n)
      opart[(size_t)p * 1024 + r * 64 + n * 16 + lr] = o[n][j];
  }
}

// ---------------- Kernel 3: combine split-KV partials -----------------------
__global__ __launch_bounds__(256) void combine_k(const float* __restrict__ opart,
                                                 const float* __restrict__ m_l,
                                                 float* __restrict__ out, int S) {
  const float LOG2E = 1.44269504f;
  int idx = blockIdx.x * 256 + threadIdx.x;     // 0 .. NROW*64-1
  int col = idx & 63;
  int row = idx >> 6;                            // b*2048 + qt*16 + r
  int b = row >> 11, t = row & 2047;
  int qt = t >> 4, r = t & 15;
  int pb = (b * 128 + qt) * S;
  float M = -INFINITY;
  for (int s = 0; s < S; ++s) M = fmaxf(M, m_l[(pb + s) * 32 + r]);
  float l = 0.f, o = 0.f;
  for (int s = 0; s < S; ++s) {
    float ms = m_l[(pb + s) * 32 + r];
    float w  = exp2f((ms - M) * LOG2E);          // 0 for ms = -inf
    l += m_l[(pb + s) * 32 + 16 + r] * w;
    o += opart[(size_t)(pb + s) * 1024 + r * 64 + col] * w;
  }
  out[(size_t)row * HDIM + col] = o / l;
}

// ---------------- launch ----------------------------------------------------
extern "C" void kernel_launch(void* const* d_in, const int* in_sizes, int n_in,
                              void* d_out, int out_size, void* d_ws, size_t ws_size,
                              hipStream_t stream) {
  const float* x  = (const float*)d_in[0];
  const float* wq = (const float*)d_in[1];
  const float* wk = (const float*)d_in[2];
  const float* wv = (const float*)d_in[3];
  float* outp = (float*)d_out;

  const size_t bf_bytes = ((size_t)3 * NROW * HDIM + 3 * 65536) * 2;
  int S = 4;
  while (S > 1 && (size_t)NQT * S * (32 + 1024) * 4 + bf_bytes > ws_size) S >>= 1;

  float* m_l   = (float*)d_ws;                          // [NQT*S][32]
  float* opart = m_l + (size_t)NQT * S * 32;            // [NQT*S][16][64]
  unsigned short* qbuf = (unsigned short*)(opart + (size_t)NQT * S * 1024);
  unsigned short* kbuf = qbuf + (size_t)NROW * HDIM;
  unsigned short* vbuf = kbuf + (size_t)NROW * HDIM;    // [B][64][T]
  unsigned short* wt   = vbuf + (size_t)NROW * HDIM;    // [3][64][1024]

  hipLaunchKernelGGL(wtrans_k, dim3(48), dim3(256), 0, stream, wq, wk, wv, wt);
  hipLaunchKernelGGL(qkv_proj_k, dim3(NROW / 16), dim3(256), 0, stream, x, wt, qbuf, kbuf, vbuf);
  hipLaunchKernelGGL(attn_k, dim3(NQT * S), dim3(64), 0, stream, qbuf, kbuf, vbuf, opart, m_l, S);
  hipLaunchKernelGGL(combine_k, dim3(NROW * HDIM / 256), dim3(256), 0, stream, opart, m_l, outp, S);
}

// Round 4
// 162.593 us; speedup vs baseline: 1.5589x; 1.1637x over previous
//
#include <hip/hip_runtime.h>

// Dtype contract: device buffers FP32 (reference dtypes); internal bf16 MFMA,
// fp32 accumulate. Tolerance is bf16-grade (2% of absmax).

#define BATCH 8
#define SEQ   2048
#define CIN   1024
#define HDIM  64
#define NROW  (BATCH * SEQ)      // 16384
#define NQT   (NROW / 16)        // 1024 q-tiles

typedef __attribute__((ext_vector_type(8))) short bf16x8;
typedef __attribute__((ext_vector_type(4))) short u16x4;
typedef __attribute__((ext_vector_type(4))) float f32x4;

__device__ __forceinline__ unsigned short f2bf(float f) {
  unsigned int u = __builtin_bit_cast(unsigned int, f);
  u += 0x7fffu + ((u >> 16) & 1u);          // RNE
  return (unsigned short)(u >> 16);
}
__device__ __forceinline__ float bf2f(unsigned short h) {
  return __builtin_bit_cast(float, (unsigned int)h << 16);
}
__device__ __forceinline__ u16x4 pack4(f32x4 a) {
  u16x4 r;
  r[0] = (short)f2bf(a[0]); r[1] = (short)f2bf(a[1]);
  r[2] = (short)f2bf(a[2]); r[3] = (short)f2bf(a[3]);
  return r;
}

// ---------------- Kernel 0: W [C][HD] fp32 -> Wt [HD][C] bf16 (LDS tiles) ---
__global__ __launch_bounds__(256) void wtrans_k(const float* __restrict__ wq,
                                                const float* __restrict__ wk,
                                                const float* __restrict__ wv,
                                                unsigned short* __restrict__ wt) {
  __shared__ unsigned short lds[64][65];
  const int m  = blockIdx.x >> 4;
  const int c0 = (blockIdx.x & 15) * 64;
  const float* w = (m == 0) ? wq : (m == 1) ? wk : wv;
  const int nl = threadIdx.x & 63, gr = threadIdx.x >> 6;
#pragma unroll
  for (int i = 0; i < 16; ++i) {
    int cl = gr * 16 + i;
    lds[cl][nl] = f2bf(w[(size_t)(c0 + cl) * HDIM + nl]);
  }
  __syncthreads();
#pragma unroll
  for (int i = 0; i < 16; ++i) {
    int n = gr * 16 + i;
    wt[(size_t)m * 65536 + n * CIN + c0 + nl] = lds[nl][n];
  }
}

// ---------------- Kernel 1: QKV projection, LDS-staged GEMM -----------------
// 512 blocks x 512 thr (8 waves). Block: 32 rows x 192 cols, K-steps of 64.
// LDS: x-tile [32][64] bf16 (4KB) + wt-tile [192][64] bf16 (24.6KB), both
// XOR-swizzled (granule ^= row&7) for conflict-free ds_read_b128.
// Wave (wm,wn): 16 rows x 48 cols (3 N-frags).
__global__ __launch_bounds__(512) void qkv_proj_k(const float* __restrict__ x,
                                                  const unsigned short* __restrict__ wt,
                                                  unsigned short* __restrict__ q,
                                                  unsigned short* __restrict__ k,
                                                  unsigned short* __restrict__ vt) {
  __shared__ __align__(16) unsigned char ldsb[28672];   // x @0, wt @4096
  const int tid  = threadIdx.x;
  const int lane = tid & 63;
  const int w    = tid >> 6;
  const int lr   = lane & 15, lg = lane >> 4;
  const int wm   = w & 1, wn = w >> 1;
  const int row0 = blockIdx.x * 32;

  // staging maps
  const int trow  = tid >> 4;               // x: 0..31
  const int tcol4 = (tid & 15) * 4;
  const float* xg = x + (size_t)(row0 + trow) * CIN + tcol4;
  const int xoff  = trow * 128 + (((tcol4 >> 3) ^ (trow & 7)) << 4) + ((tcol4 & 4) << 1);

  const int wrow_ = tid >> 3;               // 0..63 (chunk-local)
  const int wg8   = tid & 7;
  const unsigned short* wg[3];
  int woff[3];
#pragma unroll
  for (int c = 0; c < 3; ++c) {
    int wrow = c * 64 + wrow_;
    wg[c]   = wt + (size_t)wrow * CIN + wg8 * 8;
    woff[c] = 4096 + wrow * 128 + ((wg8 ^ (wrow & 7)) << 4);
  }

  f32x4 acc[3];
#pragma unroll
  for (int i = 0; i < 3; ++i) acc[i] = (f32x4){0.f, 0.f, 0.f, 0.f};

  const int arow_off = (wm * 16 + lr) * 128;
  const int brow0    = wn * 48 + lr;

#pragma unroll 1
  for (int t = 0; t < 16; ++t) {
    const int k0 = t * 64;
    // issue global loads early (latency hides under other waves' compute)
    f32x4 xv = *(const f32x4*)(xg + k0);
    bf16x8 w0 = *(const bf16x8*)(wg[0] + k0);
    bf16x8 w1 = *(const bf16x8*)(wg[1] + k0);
    bf16x8 w2 = *(const bf16x8*)(wg[2] + k0);
    __syncthreads();                         // previous compute done
    *(u16x4*)(void*)(ldsb + xoff)    = pack4(xv);
    *(bf16x8*)(void*)(ldsb + woff[0]) = w0;
    *(bf16x8*)(void*)(ldsb + woff[1]) = w1;
    *(bf16x8*)(void*)(ldsb + woff[2]) = w2;
    __syncthreads();                         // tile staged
#pragma unroll
    for (int kk = 0; kk < 2; ++kk) {
      const int swz = (((kk << 2) | lg) ^ (lr & 7)) << 4;
      bf16x8 af = *(const bf16x8*)(void*)(ldsb + arow_off + swz);
#pragma unroll
      for (int f = 0; f < 3; ++f) {
        bf16x8 bf_ = *(const bf16x8*)(void*)(ldsb + 4096 + (brow0 + f * 16) * 128 + swz);
        acc[f] = __builtin_amdgcn_mfma_f32_16x16x32_bf16(af, bf_, acc[f], 0, 0, 0);
      }
    }
  }

  // C/D: row = lg*4+j (x-row in 16), col = lr (wt-row in 16)  [m89/m91]
#pragma unroll
  for (int f = 0; f < 3; ++f) {
    const int gc  = wn * 48 + f * 16;
    const int mat = gc >> 6;
    const int hd  = (gc & 63) + lr;
#pragma unroll
    for (int j = 0; j < 4; ++j) {
      int grow = row0 + wm * 16 + lg * 4 + j;
      float v = acc[f][j];
      if (mat == 0) {
        q[(size_t)grow * HDIM + hd] = f2bf(v * 0.03125f);   // fold 1/sqrt(C)
      } else if (mat == 1) {
        k[(size_t)grow * HDIM + hd] = f2bf(v);
      } else {
        int b = grow >> 11, tp = grow & 2047;
        vt[((size_t)b * HDIM + hd) * SEQ + tp] = f2bf(v);
      }
    }
  }
}

// ---------------- Kernel 2: causal flash attention, split-KV, KVBLK=64 ------
__global__ __launch_bounds__(64) void attn_k(const unsigned short* __restrict__ q,
                                             const unsigned short* __restrict__ k,
                                             const unsigned short* __restrict__ vt,
                                             float* __restrict__ opart,
                                             float* __restrict__ m_l,
                                             int S) {
  __shared__ __align__(16) unsigned short plds[16][72];   // 144B stride: 2-way banks
  const int lane = threadIdx.x;
  const int lr = lane & 15, lg = lane >> 4;
  const int blk  = blockIdx.x;
  const int b    = blk & 7;
  const int rest = blk >> 3;
  const int s    = rest % S;
  const int qt   = 127 - rest / S;          // longest q-tiles first
  const int row0 = qt * 16;
  const int p    = (b * 128 + qt) * S + s;

  const unsigned short* qb_ = q  + (size_t)b * SEQ * HDIM;
  const unsigned short* kb_ = k  + (size_t)b * SEQ * HDIM;
  const unsigned short* vb_ = vt + (size_t)b * HDIM * SEQ;

  bf16x8 qf0 = *(const bf16x8*)(qb_ + (row0 + lr) * HDIM + lg * 8);
  bf16x8 qf1 = *(const bf16x8*)(qb_ + (row0 + lr) * HDIM + 32 + lg * 8);

  f32x4 o[4];
#pragma unroll
  for (int n = 0; n < 4; ++n) o[n] = (f32x4){0.f, 0.f, 0.f, 0.f};
  float m_run = -INFINITY, l_run = 0.f;
  const int   qrow = row0 + lr;
  const float LOG2E = 1.44269504f;
  const int nt = (row0 + 79) >> 6;          // ceil((row0+16)/64) KV tiles of 64
  const int lo = (nt * s) / S;
  const int hi = (nt * (s + 1)) / S;

  for (int t = lo; t < hi; ++t) {
    const int kv = t * 64;
    f32x4 sv[4];
#pragma unroll
    for (int f = 0; f < 4; ++f) sv[f] = (f32x4){0.f, 0.f, 0.f, 0.f};
#pragma unroll
    for (int f = 0; f < 4; ++f) {
      bf16x8 ka0 = *(const bf16x8*)(kb_ + (kv + f * 16 + lr) * HDIM + lg * 8);
      bf16x8 ka1 = *(const bf16x8*)(kb_ + (kv + f * 16 + lr) * HDIM + 32 + lg * 8);
      sv[f] = __builtin_amdgcn_mfma_f32_16x16x32_bf16(ka0, qf0, sv[f], 0, 0, 0);
      sv[f] = __builtin_amdgcn_mfma_f32_16x16x32_bf16(ka1, qf1, sv[f], 0, 0, 0);
    }
    if (kv + 63 > row0) {                    // wave-uniform: tile touches diagonal
#pragma unroll
      for (int f = 0; f < 4; ++f)
#pragma unroll
        for (int j = 0; j < 4; ++j)
          if (kv + f * 16 + lg * 4 + j > qrow) sv[f][j] = -INFINITY;
    }
    float tm = -INFINITY;
#pragma unroll
    for (int f = 0; f < 4; ++f)
#pragma unroll
      for (int j = 0; j < 4; ++j) tm = fmaxf(tm, sv[f][j]);
    tm = fmaxf(tm, __shfl_xor(tm, 16, 64));
    tm = fmaxf(tm, __shfl_xor(tm, 32, 64));
    float m_new = fmaxf(m_run, tm);
    float alpha = (m_run == -INFINITY) ? 0.f : exp2f((m_run - m_new) * LOG2E);
    float mc    = (m_new == -INFINITY) ? 0.f : m_new * LOG2E;
    float ps = 0.f;
#pragma unroll
    for (int f = 0; f < 4; ++f) {
      float p0 = exp2f(sv[f][0] * LOG2E - mc);
      float p1 = exp2f(sv[f][1] * LOG2E - mc);
      float p2 = exp2f(sv[f][2] * LOG2E - mc);
      float p3 = exp2f(sv[f][3] * LOG2E - mc);
      unsigned short r0 = f2bf(p0), r1 = f2bf(p1), r2 = f2bf(p2), r3 = f2bf(p3);
      *(unsigned int*)(&plds[lr][f * 16 + lg * 4])     = (unsigned int)r0 | ((unsigned int)r1 << 16);
      *(unsigned int*)(&plds[lr][f * 16 + lg * 4 + 2]) = (unsigned int)r2 | ((unsigned int)r3 << 16);
      ps += bf2f(r0) + bf2f(r1) + bf2f(r2) + bf2f(r3);
    }
    ps += __shfl_xor(ps, 16, 64);
    ps += __shfl_xor(ps, 32, 64);
    l_run = l_run * alpha + ps;
    m_run = m_new;
#pragma unroll
    for (int j = 0; j < 4; ++j) {
      float aj = __shfl(alpha, lg * 4 + j, 64);
      o[0][j] *= aj; o[1][j] *= aj; o[2][j] *= aj; o[3][j] *= aj;
    }
    __syncthreads();
#pragma unroll
    for (int kk = 0; kk < 2; ++kk) {
      bf16x8 pf = *(const bf16x8*)(&plds[lr][kk * 32 + lg * 8]);
#pragma unroll
      for (int n = 0; n < 4; ++n) {
        bf16x8 vf = *(const bf16x8*)(vb_ + (n * 16 + lr) * SEQ + kv + kk * 32 + lg * 8);
        o[n] = __builtin_amdgcn_mfma_f32_16x16x32_bf16(pf, vf, o[n], 0, 0, 0);
      }
    }
    __syncthreads();                         // PV reads done before next overwrite
  }

  if (lane < 16) {
    m_l[p * 32 + lane]      = m_run;
    m_l[p * 32 + 16 + lane] = l_run;
  }
#pragma unroll
  for (int j = 0; j < 4; ++j) {
    int r = lg * 4 + j;
#pragma unroll
    for (int n = 0; n < 4; ++n)
      opart[(size_t)p * 1024 + r * 64 + n * 16 + lr] = o[n][j];
  }
}

// ---------------- Kernel 3: combine split-KV partials -----------------------
__global__ __launch_bounds__(256) void combine_k(const float* __restrict__ opart,
                                                 const float* __restrict__ m_l,
                                                 float* __restrict__ out, int S) {
  const float LOG2E = 1.44269504f;
  int idx = blockIdx.x * 256 + threadIdx.x;
  int col = idx & 63;
  int row = idx >> 6;
  int b = row >> 11, t = row & 2047;
  int qt = t >> 4, r = t & 15;
  int pb = (b * 128 + qt) * S;
  float M = -INFINITY;
  for (int s = 0; s < S; ++s) M = fmaxf(M, m_l[(pb + s) * 32 + r]);
  float l = 0.f, o = 0.f;
  for (int s = 0; s < S; ++s) {
    float ms = m_l[(pb + s) * 32 + r];
    float w  = exp2f((ms - M) * LOG2E);
    l += m_l[(pb + s) * 32 + 16 + r] * w;
    o += opart[(size_t)(pb + s) * 1024 + r * 64 + col] * w;
  }
  out[(size_t)row * HDIM + col] = o / l;
}

// ---------------- launch ----------------------------------------------------
extern "C" void kernel_launch(void* const* d_in, const int* in_sizes, int n_in,
                              void* d_out, int out_size, void* d_ws, size_t ws_size,
                              hipStream_t stream) {
  const float* x  = (const float*)d_in[0];
  const float* wq = (const float*)d_in[1];
  const float* wk = (const float*)d_in[2];
  const float* wv = (const float*)d_in[3];
  float* outp = (float*)d_out;

  const size_t bf_bytes = ((size_t)3 * NROW * HDIM + 3 * 65536) * 2;
  int S = 4;
  while (S > 1 && (size_t)NQT * S * (32 + 1024) * 4 + bf_bytes > ws_size) S >>= 1;

  float* m_l   = (float*)d_ws;                          // [NQT*S][32]
  float* opart = m_l + (size_t)NQT * S * 32;            // [NQT*S][16][64]
  unsigned short* qbuf = (unsigned short*)(opart + (size_t)NQT * S * 1024);
  unsigned short* kbuf = qbuf + (size_t)NROW * HDIM;
  unsigned short* vbuf = kbuf + (size_t)NROW * HDIM;    // [B][64][T]
  unsigned short* wt   = vbuf + (size_t)NROW * HDIM;    // [3][64][1024]

  hipLaunchKernelGGL(wtrans_k, dim3(48), dim3(256), 0, stream, wq, wk, wv, wt);
  hipLaunchKernelGGL(qkv_proj_k, dim3(NROW / 32), dim3(512), 0, stream, x, wt, qbuf, kbuf, vbuf);
  hipLaunchKernelGGL(attn_k, dim3(NQT * S), dim3(64), 0, stream, qbuf, kbuf, vbuf, opart, m_l, S);
  hipLaunchKernelGGL(combine_k, dim3(NROW * HDIM / 256), dim3(256), 0, stream, opart, m_l, outp, S);
}

// Round 5
// 162.174 us; speedup vs baseline: 1.5630x; 1.0026x over previous
//
#include <hip/hip_runtime.h>

// Dtype contract: device buffers FP32 (reference dtypes); internal bf16 MFMA,
// fp32 accumulate. Tolerance is bf16-grade (2% of absmax).

#define BATCH 8
#define SEQ   2048
#define CIN   1024
#define HDIM  64
#define NROW  (BATCH * SEQ)      // 16384
#define NQT   (NROW / 16)        // 1024 q-tiles

typedef __attribute__((ext_vector_type(8))) short bf16x8;
typedef __attribute__((ext_vector_type(4))) short u16x4;
typedef __attribute__((ext_vector_type(4))) float f32x4;

__device__ __forceinline__ unsigned short f2bf(float f) {
  unsigned int u = __builtin_bit_cast(unsigned int, f);
  u += 0x7fffu + ((u >> 16) & 1u);          // RNE
  return (unsigned short)(u >> 16);
}
__device__ __forceinline__ float bf2f(unsigned short h) {
  return __builtin_bit_cast(float, (unsigned int)h << 16);
}
__device__ __forceinline__ u16x4 pack4(f32x4 a) {
  u16x4 r;
  r[0] = (short)f2bf(a[0]); r[1] = (short)f2bf(a[1]);
  r[2] = (short)f2bf(a[2]); r[3] = (short)f2bf(a[3]);
  return r;
}

// ---------------- Kernel 0: W [C][HD] fp32 -> Wt [HD][C] bf16 (LDS tiles) ---
__global__ __launch_bounds__(256) void wtrans_k(const float* __restrict__ wq,
                                                const float* __restrict__ wk,
                                                const float* __restrict__ wv,
                                                unsigned short* __restrict__ wt) {
  __shared__ unsigned short lds[64][65];
  const int m  = blockIdx.x >> 4;
  const int c0 = (blockIdx.x & 15) * 64;
  const float* w = (m == 0) ? wq : (m == 1) ? wk : wv;
  const int nl = threadIdx.x & 63, gr = threadIdx.x >> 6;
#pragma unroll
  for (int i = 0; i < 16; ++i) {
    int cl = gr * 16 + i;
    lds[cl][nl] = f2bf(w[(size_t)(c0 + cl) * HDIM + nl]);
  }
  __syncthreads();
#pragma unroll
  for (int i = 0; i < 16; ++i) {
    int n = gr * 16 + i;
    wt[(size_t)m * 65536 + n * CIN + c0 + nl] = lds[nl][n];
  }
}

// ---------------- Kernel 1: QKV projection, LDS-staged GEMM -----------------
// (unchanged from round 4; <41 us, no longer the bottleneck)
__global__ __launch_bounds__(512) void qkv_proj_k(const float* __restrict__ x,
                                                  const unsigned short* __restrict__ wt,
                                                  unsigned short* __restrict__ q,
                                                  unsigned short* __restrict__ k,
                                                  unsigned short* __restrict__ vt) {
  __shared__ __align__(16) unsigned char ldsb[28672];   // x @0, wt @4096
  const int tid  = threadIdx.x;
  const int lane = tid & 63;
  const int w    = tid >> 6;
  const int lr   = lane & 15, lg = lane >> 4;
  const int wm   = w & 1, wn = w >> 1;
  const int row0 = blockIdx.x * 32;

  const int trow  = tid >> 4;
  const int tcol4 = (tid & 15) * 4;
  const float* xg = x + (size_t)(row0 + trow) * CIN + tcol4;
  const int xoff  = trow * 128 + (((tcol4 >> 3) ^ (trow & 7)) << 4) + ((tcol4 & 4) << 1);

  const int wrow_ = tid >> 3;
  const int wg8   = tid & 7;
  const unsigned short* wg[3];
  int woff[3];
#pragma unroll
  for (int c = 0; c < 3; ++c) {
    int wrow = c * 64 + wrow_;
    wg[c]   = wt + (size_t)wrow * CIN + wg8 * 8;
    woff[c] = 4096 + wrow * 128 + ((wg8 ^ (wrow & 7)) << 4);
  }

  f32x4 acc[3];
#pragma unroll
  for (int i = 0; i < 3; ++i) acc[i] = (f32x4){0.f, 0.f, 0.f, 0.f};

  const int arow_off = (wm * 16 + lr) * 128;
  const int brow0    = wn * 48 + lr;

#pragma unroll 1
  for (int t = 0; t < 16; ++t) {
    const int k0 = t * 64;
    f32x4 xv = *(const f32x4*)(xg + k0);
    bf16x8 w0 = *(const bf16x8*)(wg[0] + k0);
    bf16x8 w1 = *(const bf16x8*)(wg[1] + k0);
    bf16x8 w2 = *(const bf16x8*)(wg[2] + k0);
    __syncthreads();
    *(u16x4*)(void*)(ldsb + xoff)    = pack4(xv);
    *(bf16x8*)(void*)(ldsb + woff[0]) = w0;
    *(bf16x8*)(void*)(ldsb + woff[1]) = w1;
    *(bf16x8*)(void*)(ldsb + woff[2]) = w2;
    __syncthreads();
#pragma unroll
    for (int kk = 0; kk < 2; ++kk) {
      const int swz = (((kk << 2) | lg) ^ (lr & 7)) << 4;
      bf16x8 af = *(const bf16x8*)(void*)(ldsb + arow_off + swz);
#pragma unroll
      for (int f = 0; f < 3; ++f) {
        bf16x8 bf_ = *(const bf16x8*)(void*)(ldsb + 4096 + (brow0 + f * 16) * 128 + swz);
        acc[f] = __builtin_amdgcn_mfma_f32_16x16x32_bf16(af, bf_, acc[f], 0, 0, 0);
      }
    }
  }

#pragma unroll
  for (int f = 0; f < 3; ++f) {
    const int gc  = wn * 48 + f * 16;
    const int mat = gc >> 6;
    const int hd  = (gc & 63) + lr;
#pragma unroll
    for (int j = 0; j < 4; ++j) {
      int grow = row0 + wm * 16 + lg * 4 + j;
      float v = acc[f][j];
      if (mat == 0) {
        q[(size_t)grow * HDIM + hd] = f2bf(v * 0.03125f);   // fold 1/sqrt(C)
      } else if (mat == 1) {
        k[(size_t)grow * HDIM + hd] = f2bf(v);
      } else {
        int b = grow >> 11, tp = grow & 2047;
        vt[((size_t)b * HDIM + hd) * SEQ + tp] = f2bf(v);
      }
    }
  }
}

// ---------------- Kernel 2: causal flash attention, split-KV, KVBLK=64 ------
// 4 independent waves per 256-thr block (lifts wg/CU dispatch limit); per-wave
// LDS slice, NO block barriers; K(t+1) register-prefetch + early V issue.
__global__ __launch_bounds__(256) void attn_k(const unsigned short* __restrict__ q,
                                              const unsigned short* __restrict__ k,
                                              const unsigned short* __restrict__ vt,
                                              float* __restrict__ opart,
                                              float* __restrict__ m_l,
                                              int S) {
  __shared__ __align__(16) unsigned short plds[4][16][72];  // 144B row stride
  const int lane = threadIdx.x & 63;
  const int w    = threadIdx.x >> 6;
  const int lr = lane & 15, lg = lane >> 4;
  const int u    = blockIdx.x * 4 + w;      // wave unit
  const int b    = u & 7;
  const int rest = u >> 3;
  const int s    = rest % S;
  const int qt   = 127 - rest / S;          // longest q-tiles first
  const int row0 = qt * 16;
  const int p    = (b * 128 + qt) * S + s;
  unsigned short (*pw)[72] = plds[w];

  const unsigned short* qb_ = q  + (size_t)b * SEQ * HDIM;
  const unsigned short* kb_ = k  + (size_t)b * SEQ * HDIM;
  const unsigned short* vb_ = vt + (size_t)b * HDIM * SEQ;

  bf16x8 qf0 = *(const bf16x8*)(qb_ + (row0 + lr) * HDIM + lg * 8);
  bf16x8 qf1 = *(const bf16x8*)(qb_ + (row0 + lr) * HDIM + 32 + lg * 8);

  f32x4 o[4];
#pragma unroll
  for (int n = 0; n < 4; ++n) o[n] = (f32x4){0.f, 0.f, 0.f, 0.f};
  float m_run = -INFINITY, l_run = 0.f;
  const int   qrow = row0 + lr;
  const float LOG2E = 1.44269504f;
  const int nt = (row0 + 79) >> 6;          // ceil((row0+16)/64) KV tiles of 64
  const int lo = (nt * s) / S;
  const int hi = (nt * (s + 1)) / S;

  auto LDK = [&](int kv, bf16x8* dst) {
#pragma unroll
    for (int f = 0; f < 4; ++f) {
      dst[2 * f]     = *(const bf16x8*)(kb_ + (kv + f * 16 + lr) * HDIM + lg * 8);
      dst[2 * f + 1] = *(const bf16x8*)(kb_ + (kv + f * 16 + lr) * HDIM + 32 + lg * 8);
    }
  };

  bf16x8 ka[8];
  if (lo < hi) LDK(lo * 64, ka);

  for (int t = lo; t < hi; ++t) {
    const int kv = t * 64;
    f32x4 sv[4];
#pragma unroll
    for (int f = 0; f < 4; ++f) {
      sv[f] = (f32x4){0.f, 0.f, 0.f, 0.f};
      sv[f] = __builtin_amdgcn_mfma_f32_16x16x32_bf16(ka[2 * f],     qf0, sv[f], 0, 0, 0);
      sv[f] = __builtin_amdgcn_mfma_f32_16x16x32_bf16(ka[2 * f + 1], qf1, sv[f], 0, 0, 0);
    }
    // prefetch next K tile (hides under softmax chain)
    bf16x8 kn[8];
    const bool more = (t + 1 < hi);
    if (more) LDK(kv + 64, kn);
    // early V issue (hides under softmax chain)
    bf16x8 vf[8];
#pragma unroll
    for (int kk = 0; kk < 2; ++kk)
#pragma unroll
      for (int n = 0; n < 4; ++n)
        vf[kk * 4 + n] = *(const bf16x8*)(vb_ + (n * 16 + lr) * SEQ + kv + kk * 32 + lg * 8);

    if (kv + 63 > row0) {                    // wave-uniform: tile touches diagonal
#pragma unroll
      for (int f = 0; f < 4; ++f)
#pragma unroll
        for (int j = 0; j < 4; ++j)
          if (kv + f * 16 + lg * 4 + j > qrow) sv[f][j] = -INFINITY;
    }
    float tm = -INFINITY;
#pragma unroll
    for (int f = 0; f < 4; ++f)
#pragma unroll
      for (int j = 0; j < 4; ++j) tm = fmaxf(tm, sv[f][j]);
    tm = fmaxf(tm, __shfl_xor(tm, 16, 64));
    tm = fmaxf(tm, __shfl_xor(tm, 32, 64));
    float m_new = fmaxf(m_run, tm);
    float alpha = (m_run == -INFINITY) ? 0.f : exp2f((m_run - m_new) * LOG2E);
    float mc    = (m_new == -INFINITY) ? 0.f : m_new * LOG2E;
    float ps = 0.f;
#pragma unroll
    for (int f = 0; f < 4; ++f) {
      float p0 = exp2f(sv[f][0] * LOG2E - mc);
      float p1 = exp2f(sv[f][1] * LOG2E - mc);
      float p2 = exp2f(sv[f][2] * LOG2E - mc);
      float p3 = exp2f(sv[f][3] * LOG2E - mc);
      ps += (p0 + p1) + (p2 + p3);           // f32 sum (saves bf2f round-trips)
      unsigned int lo32 = (unsigned int)f2bf(p0) | ((unsigned int)f2bf(p1) << 16);
      unsigned int hi32 = (unsigned int)f2bf(p2) | ((unsigned int)f2bf(p3) << 16);
      uint2 pk; pk.x = lo32; pk.y = hi32;
      *(uint2*)(&pw[lr][f * 16 + lg * 4]) = pk;   // 8B-aligned ds_write_b64
    }
    ps += __shfl_xor(ps, 16, 64);
    ps += __shfl_xor(ps, 32, 64);
    l_run = l_run * alpha + ps;
    m_run = m_new;
#pragma unroll
    for (int j = 0; j < 4; ++j) {
      float aj = __shfl(alpha, lg * 4 + j, 64);
      o[0][j] *= aj; o[1][j] *= aj; o[2][j] *= aj; o[3][j] *= aj;
    }
    // in-wave sync: DS ops of one wave process in order; drain writes, then read
    asm volatile("s_waitcnt lgkmcnt(0)" ::: "memory");
    __builtin_amdgcn_sched_barrier(0);
#pragma unroll
    for (int kk = 0; kk < 2; ++kk) {
      bf16x8 pf = *(const bf16x8*)(&pw[lr][kk * 32 + lg * 8]);
#pragma unroll
      for (int n = 0; n < 4; ++n)
        o[n] = __builtin_amdgcn_mfma_f32_16x16x32_bf16(pf, vf[kk * 4 + n], o[n], 0, 0, 0);
    }
    if (more) {
#pragma unroll
      for (int f = 0; f < 8; ++f) ka[f] = kn[f];
    }
  }

  if (lane < 16) {
    m_l[p * 32 + lane]      = m_run;
    m_l[p * 32 + 16 + lane] = l_run;
  }
#pragma unroll
  for (int j = 0; j < 4; ++j) {
    int r = lg * 4 + j;
#pragma unroll
    for (int n = 0; n < 4; ++n)
      opart[(size_t)p * 1024 + r * 64 + n * 16 + lr] = o[n][j];
  }
}

// ---------------- Kernel 3: combine split-KV partials -----------------------
__global__ __launch_bounds__(256) void combine_k(const float* __restrict__ opart,
                                                 const float* __restrict__ m_l,
                                                 float* __restrict__ out, int S) {
  const float LOG2E = 1.44269504f;
  int idx = blockIdx.x * 256 + threadIdx.x;
  int col = idx & 63;
  int row = idx >> 6;
  int b = row >> 11, t = row & 2047;
  int qt = t >> 4, r = t & 15;
  int pb = (b * 128 + qt) * S;
  float M = -INFINITY;
  for (int s = 0; s < S; ++s) M = fmaxf(M, m_l[(pb + s) * 32 + r]);
  float l = 0.f, o = 0.f;
  for (int s = 0; s < S; ++s) {
    float ms = m_l[(pb + s) * 32 + r];
    float w  = exp2f((ms - M) * LOG2E);
    l += m_l[(pb + s) * 32 + 16 + r] * w;
    o += opart[(size_t)(pb + s) * 1024 + r * 64 + col] * w;
  }
  out[(size_t)row * HDIM + col] = o / l;
}

// ---------------- launch ----------------------------------------------------
extern "C" void kernel_launch(void* const* d_in, const int* in_sizes, int n_in,
                              void* d_out, int out_size, void* d_ws, size_t ws_size,
                              hipStream_t stream) {
  const float* x  = (const float*)d_in[0];
  const float* wq = (const float*)d_in[1];
  const float* wk = (const float*)d_in[2];
  const float* wv = (const float*)d_in[3];
  float* outp = (float*)d_out;

  const size_t bf_bytes = ((size_t)3 * NROW * HDIM + 3 * 65536) * 2;
  int S = 4;
  while (S > 1 && (size_t)NQT * S * (32 + 1024) * 4 + bf_bytes > ws_size) S >>= 1;

  float* m_l   = (float*)d_ws;                          // [NQT*S][32]
  float* opart = m_l + (size_t)NQT * S * 32;            // [NQT*S][16][64]
  unsigned short* qbuf = (unsigned short*)(opart + (size_t)NQT * S * 1024);
  unsigned short* kbuf = qbuf + (size_t)NROW * HDIM;
  unsigned short* vbuf = kbuf + (size_t)NROW * HDIM;    // [B][64][T]
  unsigned short* wt   = vbuf + (size_t)NROW * HDIM;    // [3][64][1024]

  hipLaunchKernelGGL(wtrans_k, dim3(48), dim3(256), 0, stream, wq, wk, wv, wt);
  hipLaunchKernelGGL(qkv_proj_k, dim3(NROW / 32), dim3(512), 0, stream, x, wt, qbuf, kbuf, vbuf);
  hipLaunchKernelGGL(attn_k, dim3(NQT * S / 4), dim3(256), 0, stream, qbuf, kbuf, vbuf, opart, m_l, S);
  hipLaunchKernelGGL(combine_k, dim3(NROW * HDIM / 256), dim3(256), 0, stream, opart, m_l, outp, S);
}